// Round 1
// baseline (37.229 us; speedup 1.0000x reference)
//
#include <hip/hip_runtime.h>
#include <stdint.h>

#define N_DIM 256
#define C_DIM 64
#define D_DIM 4096
#define KQ    1024   // k-range per wave (D/4)

typedef __bf16 bf16x8_t __attribute__((ext_vector_type(8)));
typedef float  f32x16_t __attribute__((ext_vector_type(16)));

union Frag {
  uint4     q;
  uint32_t  u[4];
  bf16x8_t  b;
};

__device__ __forceinline__ uint32_t pk_bf16(float lo, float hi) {
  uint32_t d;
  asm("v_cvt_pk_bf16_f32 %0, %1, %2" : "=v"(d) : "v"(lo), "v"(hi));
  return d;
}

#define MFMA32(a, b, c) __builtin_amdgcn_mfma_f32_32x32x16_bf16(a, b, c, 0, 0, 0)

// ---- prep: u f32 -> bf16, rearranged into MFMA-fragment subtile layout ----
// ub unit layout: [k8 = 0..511][row = 0..63][8 bf16], 16 B per unit.
__global__ __launch_bounds__(256) void prep_kernel(const float* __restrict__ u,
                                                   uint16_t* __restrict__ ub) {
  const int t   = blockIdx.x * 256 + threadIdx.x;   // 0..32767
  const int row = t >> 9;
  const int k8  = t & 511;
  const float4* p = (const float4*)(u + (size_t)row * D_DIM + (size_t)k8 * 8);
  const float4 a = p[0], b = p[1];
  uint4 o;
  o.x = pk_bf16(a.x, a.y);
  o.y = pk_bf16(a.z, a.w);
  o.z = pk_bf16(b.x, b.y);
  o.w = pk_bf16(b.z, b.w);
  *(uint4*)(ub + (size_t)(k8 * C_DIM + row) * 8) = o;
}

// ---- main: one workgroup per n; 4 waves = 4-way K-split; LDS reduce ------
template<bool PRE>
__global__ __launch_bounds__(256)
void gram_kernel(const float* __restrict__ vin,
                 const float* __restrict__ uf32,
                 const uint16_t* __restrict__ ub,
                 float* __restrict__ out)
{
  __shared__ float Lv[4][KQ];            // per-wave v quarter, 16 KB
  __shared__ float Red[4][C_DIM][20];    // reduce buffer, 80 B/row (bank-optimal)

  const int tid = threadIdx.x;
  const int w   = tid >> 6;     // wave id = K-quarter
  const int l   = tid & 63;
  const int n   = blockIdx.x;
  const int hg  = l >> 5;       // k-half-group within fragment
  const int lm  = l & 31;       // row/col within 32-tile
  const int kq  = w * KQ;

  // stage this wave's v quarter (4 KB) into LDS once, via global_load_lds
  {
    const char* vsrc = (const char*)(vin + (size_t)n * D_DIM + kq) + l * 16;
    char* vdst = (char*)&Lv[w][0];
#pragma unroll
    for (int i = 0; i < 4; ++i)
      __builtin_amdgcn_global_load_lds(
          (const __attribute__((address_space(1))) uint32_t*)(vsrc + i * 1024),
          (__attribute__((address_space(3))) uint32_t*)(vdst + i * 1024),
          16, 0, 0);
    asm volatile("s_waitcnt vmcnt(0)" ::: "memory");
  }

  f32x16_t acc[2][2];
#pragma unroll
  for (int a = 0; a < 2; ++a)
#pragma unroll
    for (int b = 0; b < 2; ++b)
#pragma unroll
      for (int i = 0; i < 16; ++i) acc[a][b][i] = 0.0f;

  const char* vbase = (const char*)&Lv[w][0] + hg * 32;

  if (PRE) {
    // fragments loaded straight from the subtiled bf16 u (coalesced, L2-resident)
    const char* up = (const char*)ub + ((size_t)(kq >> 3) + hg) * 1024 + (size_t)lm * 16;
    Frag c0, c1, n0, n1;
    c0.q = *(const uint4*)(up);        c1.q = *(const uint4*)(up + 512);
    n0.q = *(const uint4*)(up + 2048); n1.q = *(const uint4*)(up + 2560);
    up += 4096;
#pragma unroll 2
    for (int s = 0; s < 64; ++s) {
      Frag p0, p1;                               // prefetch step s+2 (ws has slack)
      p0.q = *(const uint4*)(up);
      p1.q = *(const uint4*)(up + 512);
      up += 2048;
      const float4 va = *(const float4*)(vbase + s * 64);
      const float4 vb = *(const float4*)(vbase + s * 64 + 16);
      Frag sa0, sa1;
      sa0.u[0] = pk_bf16(__uint_as_float(c0.u[0] << 16) * va.x, __uint_as_float(c0.u[0] & 0xffff0000u) * va.y);
      sa0.u[1] = pk_bf16(__uint_as_float(c0.u[1] << 16) * va.z, __uint_as_float(c0.u[1] & 0xffff0000u) * va.w);
      sa0.u[2] = pk_bf16(__uint_as_float(c0.u[2] << 16) * vb.x, __uint_as_float(c0.u[2] & 0xffff0000u) * vb.y);
      sa0.u[3] = pk_bf16(__uint_as_float(c0.u[3] << 16) * vb.z, __uint_as_float(c0.u[3] & 0xffff0000u) * vb.w);
      sa1.u[0] = pk_bf16(__uint_as_float(c1.u[0] << 16) * va.x, __uint_as_float(c1.u[0] & 0xffff0000u) * va.y);
      sa1.u[1] = pk_bf16(__uint_as_float(c1.u[1] << 16) * va.z, __uint_as_float(c1.u[1] & 0xffff0000u) * va.w);
      sa1.u[2] = pk_bf16(__uint_as_float(c1.u[2] << 16) * vb.x, __uint_as_float(c1.u[2] & 0xffff0000u) * vb.y);
      sa1.u[3] = pk_bf16(__uint_as_float(c1.u[3] << 16) * vb.z, __uint_as_float(c1.u[3] & 0xffff0000u) * vb.w);
      acc[0][0] = MFMA32(sa0.b, c0.b, acc[0][0]);
      acc[0][1] = MFMA32(sa0.b, c1.b, acc[0][1]);
      acc[1][0] = MFMA32(sa1.b, c0.b, acc[1][0]);
      acc[1][1] = MFMA32(sa1.b, c1.b, acc[1][1]);
      c0 = n0; c1 = n1; n0 = p0; n1 = p1;
    }
  } else {
    // fallback (ws too small): read u f32 directly, convert in registers
    const char* ua  = (const char*)(uf32 + (size_t)lm * D_DIM + kq) + hg * 32;
    const char* ubx = ua + (size_t)32 * D_DIM * 4;
    for (int s = 0; s < 64; ++s) {
      const float4 a0 = *(const float4*)(ua  + (size_t)s * 64);
      const float4 a1 = *(const float4*)(ua  + (size_t)s * 64 + 16);
      const float4 b0 = *(const float4*)(ubx + (size_t)s * 64);
      const float4 b1 = *(const float4*)(ubx + (size_t)s * 64 + 16);
      const float4 va = *(const float4*)(vbase + s * 64);
      const float4 vb = *(const float4*)(vbase + s * 64 + 16);
      Frag f0, f1, sa0, sa1;
      f0.u[0] = pk_bf16(a0.x, a0.y);  f0.u[1] = pk_bf16(a0.z, a0.w);
      f0.u[2] = pk_bf16(a1.x, a1.y);  f0.u[3] = pk_bf16(a1.z, a1.w);
      f1.u[0] = pk_bf16(b0.x, b0.y);  f1.u[1] = pk_bf16(b0.z, b0.w);
      f1.u[2] = pk_bf16(b1.x, b1.y);  f1.u[3] = pk_bf16(b1.z, b1.w);
      sa0.u[0] = pk_bf16(a0.x * va.x, a0.y * va.y);
      sa0.u[1] = pk_bf16(a0.z * va.z, a0.w * va.w);
      sa0.u[2] = pk_bf16(a1.x * vb.x, a1.y * vb.y);
      sa0.u[3] = pk_bf16(a1.z * vb.z, a1.w * vb.w);
      sa1.u[0] = pk_bf16(b0.x * va.x, b0.y * va.y);
      sa1.u[1] = pk_bf16(b0.z * va.z, b0.w * va.w);
      sa1.u[2] = pk_bf16(b1.x * vb.x, b1.y * vb.y);
      sa1.u[3] = pk_bf16(b1.z * vb.z, b1.w * vb.w);
      acc[0][0] = MFMA32(sa0.b, f0.b, acc[0][0]);
      acc[0][1] = MFMA32(sa0.b, f1.b, acc[0][1]);
      acc[1][0] = MFMA32(sa1.b, f0.b, acc[1][0]);
      acc[1][1] = MFMA32(sa1.b, f1.b, acc[1][1]);
    }
  }

  // ---- cross-wave (K-split) reduction, tile by tile, then store ----------
#pragma unroll
  for (int t = 0; t < 4; ++t) {
    __syncthreads();
    {
      const f32x16_t A = acc[t >> 1][t & 1];
      float* rp = &Red[w][l][0];
#pragma unroll
      for (int qq = 0; qq < 4; ++qq)
        *(float4*)(rp + qq * 4) =
            make_float4(A[qq * 4 + 0], A[qq * 4 + 1], A[qq * 4 + 2], A[qq * 4 + 3]);
    }
    __syncthreads();
    {
      const float4 r0 = *(const float4*)(&Red[0][l][w * 4]);
      const float4 r1 = *(const float4*)(&Red[1][l][w * 4]);
      const float4 r2 = *(const float4*)(&Red[2][l][w * 4]);
      const float4 r3 = *(const float4*)(&Red[3][l][w * 4]);
      const int tr = t >> 1, tc = t & 1;
      const int rbase = tr * 32 + w * 8 + ((l >> 5) << 2);   // reg rows: rbase+0..3
      const int col   = tc * 32 + (l & 31);
      float* op = out + (size_t)n * 4096 + (size_t)rbase * 64 + col;
      op[0]   = r0.x + r1.x + r2.x + r3.x;
      op[64]  = r0.y + r1.y + r2.y + r3.y;
      op[128] = r0.z + r1.z + r2.z + r3.z;
      op[192] = r0.w + r1.w + r2.w + r3.w;
    }
  }
}

extern "C" void kernel_launch(void* const* d_in, const int* in_sizes, int n_in,
                              void* d_out, int out_size, void* d_ws, size_t ws_size,
                              hipStream_t stream) {
  const float* v   = (const float*)d_in[0];
  const float* u   = (const float*)d_in[1];
  float*       out = (float*)d_out;
  // need 512 KB for bf16 u + slack for the depth-2 prefetch overrun
  if (ws_size >= (size_t)(C_DIM * D_DIM * 2 + 8192)) {
    uint16_t* ub = (uint16_t*)d_ws;
    prep_kernel<<<dim3((C_DIM * D_DIM / 8) / 256), dim3(256), 0, stream>>>(u, ub);
    gram_kernel<true><<<dim3(N_DIM), dim3(256), 0, stream>>>(v, u, ub, out);
  } else {
    gram_kernel<false><<<dim3(N_DIM), dim3(256), 0, stream>>>(v, u, nullptr, out);
  }
}

// Round 5
// 32.961 us; speedup vs baseline: 1.1295x; 1.1295x over previous
//
#include <hip/hip_runtime.h>
#include <stdint.h>

#define N_DIM 256
#define C_DIM 64
#define D_DIM 4096
#define NQ    4              // k-split ways (blocks per n)
#define KQB   (D_DIM / NQ)   // 1024 k per block
#define KWV   (KQB / 4)      // 256 k per wave
#define NSTEP (KWV / 16)     // 16 MFMA k-steps per wave
#define SLAB  (N_DIM * C_DIM * C_DIM)   // 1048576 floats per partial slab

typedef __bf16 bf16x8_t __attribute__((ext_vector_type(8)));
typedef float  f32x16_t __attribute__((ext_vector_type(16)));

union Frag {
  uint4     q;
  uint32_t  u[4];
  bf16x8_t  b;
};

__device__ __forceinline__ uint32_t pk_bf16(float lo, float hi) {
  uint32_t d;
  asm("v_cvt_pk_bf16_f32 %0, %1, %2" : "=v"(d) : "v"(lo), "v"(hi));
  return d;
}

#define MFMA32(a, b, c) __builtin_amdgcn_mfma_f32_32x32x16_bf16(a, b, c, 0, 0, 0)

// ---- prep: u f32 -> bf16, rearranged into MFMA-fragment subtile layout ----
// ub unit layout: [k8 = 0..511][row = 0..63][8 bf16], 16 B per unit. (R1-validated)
__global__ __launch_bounds__(256) void prep_kernel(const float* __restrict__ u,
                                                   uint16_t* __restrict__ ub) {
  const int t   = blockIdx.x * 256 + threadIdx.x;   // 0..32767
  const int row = t >> 9;
  const int k8  = t & 511;
  const float4* p = (const float4*)(u + (size_t)row * D_DIM + (size_t)k8 * 8);
  const float4 a = p[0], b = p[1];
  uint4 o;
  o.x = pk_bf16(a.x, a.y);
  o.y = pk_bf16(a.z, a.w);
  o.z = pk_bf16(b.x, b.y);
  o.w = pk_bf16(b.z, b.w);
  *(uint4*)(ub + (size_t)(k8 * C_DIM + row) * 8) = o;
}

// ---- gram partial: block (n,b) computes k in [b*1024,(b+1)*1024), 4 waves --
// v read directly from global (wave-broadcast, L1-resident). No LDS staging.
__global__ __launch_bounds__(256)
void gram_part_kernel(const float* __restrict__ vin,
                      const uint16_t* __restrict__ ub,
                      float* __restrict__ part)
{
  __shared__ float Red[4][C_DIM][20];    // R1-validated reduce buffer, 20 KB

  const int tid = threadIdx.x;
  const int w   = tid >> 6;     // wave id within block
  const int l   = tid & 63;
  const int bid = blockIdx.x;
  const int n   = bid & 255;    // co-launched blocks share the same ub slice
  const int b   = bid >> 8;     // k-quarter
  const int hg  = l >> 5;       // k-half-group within fragment
  const int lm  = l & 31;       // row/col within 32-tile
  const int kq  = b * KQB + w * KWV;   // this wave's k start

  f32x16_t acc[2][2];
#pragma unroll
  for (int a = 0; a < 2; ++a)
#pragma unroll
    for (int c = 0; c < 2; ++c)
#pragma unroll
      for (int i = 0; i < 16; ++i) acc[a][c][i] = 0.0f;

  // v: broadcast loads straight from global; slice is 1 KB -> L1-hot.
  const char* vg = (const char*)(vin + (size_t)n * D_DIM + kq) + hg * 32;
  // u fragments from the subtiled bf16 layout; ub (512 KB) is L2-resident.
  const char* up = (const char*)ub +
                   ((size_t)(b * 128 + w * 32 + hg)) * 1024 + (size_t)lm * 16;

#pragma unroll
  for (int s = 0; s < NSTEP; ++s) {
    Frag c0, c1;
    c0.q = *(const uint4*)(up);
    c1.q = *(const uint4*)(up + 512);
    up += 2048;
    const float4 va = *(const float4*)(vg + s * 64);
    const float4 vb = *(const float4*)(vg + s * 64 + 16);
    Frag sa0, sa1;
    sa0.u[0] = pk_bf16(__uint_as_float(c0.u[0] << 16) * va.x, __uint_as_float(c0.u[0] & 0xffff0000u) * va.y);
    sa0.u[1] = pk_bf16(__uint_as_float(c0.u[1] << 16) * va.z, __uint_as_float(c0.u[1] & 0xffff0000u) * va.w);
    sa0.u[2] = pk_bf16(__uint_as_float(c0.u[2] << 16) * vb.x, __uint_as_float(c0.u[2] & 0xffff0000u) * vb.y);
    sa0.u[3] = pk_bf16(__uint_as_float(c0.u[3] << 16) * vb.z, __uint_as_float(c0.u[3] & 0xffff0000u) * vb.w);
    sa1.u[0] = pk_bf16(__uint_as_float(c1.u[0] << 16) * va.x, __uint_as_float(c1.u[0] & 0xffff0000u) * va.y);
    sa1.u[1] = pk_bf16(__uint_as_float(c1.u[1] << 16) * va.z, __uint_as_float(c1.u[1] & 0xffff0000u) * va.w);
    sa1.u[2] = pk_bf16(__uint_as_float(c1.u[2] << 16) * vb.x, __uint_as_float(c1.u[2] & 0xffff0000u) * vb.y);
    sa1.u[3] = pk_bf16(__uint_as_float(c1.u[3] << 16) * vb.z, __uint_as_float(c1.u[3] & 0xffff0000u) * vb.w);
    acc[0][0] = MFMA32(sa0.b, c0.b, acc[0][0]);
    acc[0][1] = MFMA32(sa0.b, c1.b, acc[0][1]);
    acc[1][0] = MFMA32(sa1.b, c0.b, acc[1][0]);
    acc[1][1] = MFMA32(sa1.b, c1.b, acc[1][1]);
  }

  // ---- R1's validated cross-wave reduce; plain stores to the partial slab --
  float* slab = part + (size_t)(b * 256 + n) * 4096;
#pragma unroll
  for (int t = 0; t < 4; ++t) {
    __syncthreads();
    {
      const f32x16_t A = acc[t >> 1][t & 1];
      float* rp = &Red[w][l][0];
#pragma unroll
      for (int qq = 0; qq < 4; ++qq)
        *(float4*)(rp + qq * 4) =
            make_float4(A[qq * 4 + 0], A[qq * 4 + 1], A[qq * 4 + 2], A[qq * 4 + 3]);
    }
    __syncthreads();
    {
      const float4 r0 = *(const float4*)(&Red[0][l][w * 4]);
      const float4 r1 = *(const float4*)(&Red[1][l][w * 4]);
      const float4 r2 = *(const float4*)(&Red[2][l][w * 4]);
      const float4 r3 = *(const float4*)(&Red[3][l][w * 4]);
      const int tr = t >> 1, tc = t & 1;
      const int rbase = tr * 32 + w * 8 + ((l >> 5) << 2);   // rows rbase+0..3
      const int col   = tc * 32 + (l & 31);
      float* op = slab + (size_t)rbase * 64 + col;
      op[0]   = r0.x + r1.x + r2.x + r3.x;
      op[64]  = r0.y + r1.y + r2.y + r3.y;
      op[128] = r0.z + r1.z + r2.z + r3.z;
      op[192] = r0.w + r1.w + r2.w + r3.w;
    }
  }
}

// ---- reduce: out[i] = sum over 4 partial slabs (deterministic, coalesced) --
__global__ __launch_bounds__(256)
void reduce_kernel(const float* __restrict__ part, float* __restrict__ out) {
  const size_t i = ((size_t)blockIdx.x * 256 + threadIdx.x) * 4;
  const float4 a = *(const float4*)(part + i);
  const float4 b = *(const float4*)(part + SLAB + i);
  const float4 c = *(const float4*)(part + 2 * (size_t)SLAB + i);
  const float4 d = *(const float4*)(part + 3 * (size_t)SLAB + i);
  *(float4*)(out + i) = make_float4(a.x + b.x + c.x + d.x,
                                    a.y + b.y + c.y + d.y,
                                    a.z + b.z + c.z + d.z,
                                    a.w + b.w + c.w + d.w);
}

// ---- fallback (tiny ws): single block per n, full K, u as f32, store out --
__global__ __launch_bounds__(256)
void gram_fallback_kernel(const float* __restrict__ vin,
                          const float* __restrict__ uf32,
                          float* __restrict__ out)
{
  __shared__ float Red[4][C_DIM][20];

  const int tid = threadIdx.x;
  const int w   = tid >> 6;
  const int l   = tid & 63;
  const int n   = blockIdx.x;
  const int hg  = l >> 5;
  const int lm  = l & 31;
  const int kq  = w * 1024;

  f32x16_t acc[2][2];
#pragma unroll
  for (int a = 0; a < 2; ++a)
#pragma unroll
    for (int c = 0; c < 2; ++c)
#pragma unroll
      for (int i = 0; i < 16; ++i) acc[a][c][i] = 0.0f;

  const char* vg  = (const char*)(vin + (size_t)n * D_DIM + kq) + hg * 32;
  const char* ua  = (const char*)(uf32 + (size_t)lm * D_DIM + kq) + hg * 32;
  const char* ubx = ua + (size_t)32 * D_DIM * 4;
  for (int s = 0; s < 64; ++s) {
    const float4 a0 = *(const float4*)(ua  + (size_t)s * 64);
    const float4 a1 = *(const float4*)(ua  + (size_t)s * 64 + 16);
    const float4 b0 = *(const float4*)(ubx + (size_t)s * 64);
    const float4 b1 = *(const float4*)(ubx + (size_t)s * 64 + 16);
    const float4 va = *(const float4*)(vg + s * 64);
    const float4 vb = *(const float4*)(vg + s * 64 + 16);
    Frag f0, f1, sa0, sa1;
    f0.u[0] = pk_bf16(a0.x, a0.y);  f0.u[1] = pk_bf16(a0.z, a0.w);
    f0.u[2] = pk_bf16(a1.x, a1.y);  f0.u[3] = pk_bf16(a1.z, a1.w);
    f1.u[0] = pk_bf16(b0.x, b0.y);  f1.u[1] = pk_bf16(b0.z, b0.w);
    f1.u[2] = pk_bf16(b1.x, b1.y);  f1.u[3] = pk_bf16(b1.z, b1.w);
    sa0.u[0] = pk_bf16(a0.x * va.x, a0.y * va.y);
    sa0.u[1] = pk_bf16(a0.z * va.z, a0.w * va.w);
    sa0.u[2] = pk_bf16(a1.x * vb.x, a1.y * vb.y);
    sa0.u[3] = pk_bf16(a1.z * vb.z, a1.w * vb.w);
    sa1.u[0] = pk_bf16(b0.x * va.x, b0.y * va.y);
    sa1.u[1] = pk_bf16(b0.z * va.z, b0.w * va.w);
    sa1.u[2] = pk_bf16(b1.x * vb.x, b1.y * vb.y);
    sa1.u[3] = pk_bf16(b1.z * vb.z, b1.w * vb.w);
    acc[0][0] = MFMA32(sa0.b, f0.b, acc[0][0]);
    acc[0][1] = MFMA32(sa0.b, f1.b, acc[0][1]);
    acc[1][0] = MFMA32(sa1.b, f0.b, acc[1][0]);
    acc[1][1] = MFMA32(sa1.b, f1.b, acc[1][1]);
  }

#pragma unroll
  for (int t = 0; t < 4; ++t) {
    __syncthreads();
    {
      const f32x16_t A = acc[t >> 1][t & 1];
      float* rp = &Red[w][l][0];
#pragma unroll
      for (int qq = 0; qq < 4; ++qq)
        *(float4*)(rp + qq * 4) =
            make_float4(A[qq * 4 + 0], A[qq * 4 + 1], A[qq * 4 + 2], A[qq * 4 + 3]);
    }
    __syncthreads();
    {
      const float4 r0 = *(const float4*)(&Red[0][l][w * 4]);
      const float4 r1 = *(const float4*)(&Red[1][l][w * 4]);
      const float4 r2 = *(const float4*)(&Red[2][l][w * 4]);
      const float4 r3 = *(const float4*)(&Red[3][l][w * 4]);
      const int tr = t >> 1, tc = t & 1;
      const int rbase = tr * 32 + w * 8 + ((l >> 5) << 2);
      const int col   = tc * 32 + (l & 31);
      float* op = out + (size_t)n * 4096 + (size_t)rbase * 64 + col;
      op[0]   = r0.x + r1.x + r2.x + r3.x;
      op[64]  = r0.y + r1.y + r2.y + r3.y;
      op[128] = r0.z + r1.z + r2.z + r3.z;
      op[192] = r0.w + r1.w + r2.w + r3.w;
    }
  }
}

extern "C" void kernel_launch(void* const* d_in, const int* in_sizes, int n_in,
                              void* d_out, int out_size, void* d_ws, size_t ws_size,
                              hipStream_t stream) {
  const float* v   = (const float*)d_in[0];
  const float* u   = (const float*)d_in[1];
  float*       out = (float*)d_out;
  // layout: ub (512 KB) at ws+0; partial slabs (16 MB) at ws+1MB
  if (ws_size >= ((size_t)18 << 20)) {
    uint16_t* ub   = (uint16_t*)d_ws;
    float*    part = (float*)((char*)d_ws + (1u << 20));
    prep_kernel<<<dim3((C_DIM * D_DIM / 8) / 256), dim3(256), 0, stream>>>(u, ub);
    gram_part_kernel<<<dim3(N_DIM * NQ), dim3(256), 0, stream>>>(v, ub, part);
    reduce_kernel<<<dim3(SLAB / 4 / 256), dim3(256), 0, stream>>>(part, out);
  } else {
    gram_fallback_kernel<<<dim3(N_DIM), dim3(256), 0, stream>>>(v, u, out);
  }
}

// Round 6
// 32.849 us; speedup vs baseline: 1.1333x; 1.0034x over previous
//
#include <hip/hip_runtime.h>
#include <stdint.h>

#define N_DIM 256
#define C_DIM 64
#define D_DIM 4096
#define NQ    4              // k-split ways (blocks per n)
#define KQB   (D_DIM / NQ)   // 1024 k per block
#define KWV   (KQB / 4)      // 256 k per wave
#define NSTEP (KWV / 16)     // 16 MFMA k-steps per wave
#define SLAB  (N_DIM * C_DIM * C_DIM)   // 1048576 floats per partial slab

// ws layout: uh (f16 u, 512 KB) @0; vh (f16 v, 2 MB) @1MB; part (16 MB) @4MB
#define VH_OFF   (1u << 20)
#define PART_OFF (4u << 20)

typedef __bf16    bf16x8_t __attribute__((ext_vector_type(8)));
typedef _Float16  f16x8_t  __attribute__((ext_vector_type(8)));
typedef float     f32x16_t __attribute__((ext_vector_type(16)));

union Frag {
  uint4     q;
  uint32_t  u[4];
  bf16x8_t  b;
};
union FragH {
  uint4     q;
  _Float16  h[8];
  f16x8_t   v;
};

__device__ __forceinline__ uint32_t pk_bf16(float lo, float hi) {
  uint32_t d;
  asm("v_cvt_pk_bf16_f32 %0, %1, %2" : "=v"(d) : "v"(lo), "v"(hi));
  return d;
}

#define MFMA32H(a, b, c) __builtin_amdgcn_mfma_f32_32x32x16_f16(a, b, c, 0, 0, 0)
#define MFMA32B(a, b, c) __builtin_amdgcn_mfma_f32_32x32x16_bf16(a, b, c, 0, 0, 0)

// ---- prep: u f32 -> f16 subtile layout; v f32 -> f16 plain layout ---------
// u part (blocks 0..127): t in [0,32768): row=t>>9, k8=t&511 (R5-validated map)
// v part (blocks 128..639): 8 elems per thread, plain copy-convert.
__global__ __launch_bounds__(256) void prep_kernel(const float* __restrict__ u,
                                                   const float* __restrict__ v,
                                                   _Float16* __restrict__ uh,
                                                   _Float16* __restrict__ vh) {
  const int gid = blockIdx.x * 256 + threadIdx.x;
  if (blockIdx.x < 128) {
    const int t   = gid;                 // 0..32767
    const int row = t >> 9;
    const int k8  = t & 511;
    const float4* p = (const float4*)(u + (size_t)row * D_DIM + (size_t)k8 * 8);
    const float4 a = p[0], b = p[1];
    FragH o;
    o.h[0] = (_Float16)a.x; o.h[1] = (_Float16)a.y;
    o.h[2] = (_Float16)a.z; o.h[3] = (_Float16)a.w;
    o.h[4] = (_Float16)b.x; o.h[5] = (_Float16)b.y;
    o.h[6] = (_Float16)b.z; o.h[7] = (_Float16)b.w;
    *(uint4*)(uh + (size_t)(k8 * C_DIM + row) * 8) = o.q;
  } else {
    const int t = gid - 32768;           // 0..131071, 8 elems each
    const float4* p = (const float4*)(v + (size_t)t * 8);
    const float4 a = p[0], b = p[1];
    FragH o;
    o.h[0] = (_Float16)a.x; o.h[1] = (_Float16)a.y;
    o.h[2] = (_Float16)a.z; o.h[3] = (_Float16)a.w;
    o.h[4] = (_Float16)b.x; o.h[5] = (_Float16)b.y;
    o.h[6] = (_Float16)b.z; o.h[7] = (_Float16)b.w;
    *(uint4*)(vh + (size_t)t * 8) = o.q;
  }
}

// ---- gram partial: block (n,b), 4 waves, f16 datapath, depth-2 prefetch ---
__global__ __launch_bounds__(256, 4)
void gram_part_kernel(const _Float16* __restrict__ vh,
                      const _Float16* __restrict__ uh,
                      float* __restrict__ part)
{
  __shared__ float Red[4][C_DIM][20];    // R1/R5-validated reduce buffer

  const int tid = threadIdx.x;
  const int w   = tid >> 6;
  const int l   = tid & 63;
  const int bid = blockIdx.x;
  const int n   = bid & 255;
  const int b   = bid >> 8;
  const int hg  = l >> 5;
  const int lm  = l & 31;
  const int kq  = b * KQB + w * KWV;

  f32x16_t acc[2][2];
#pragma unroll
  for (int a = 0; a < 2; ++a)
#pragma unroll
    for (int c = 0; c < 2; ++c)
#pragma unroll
      for (int i = 0; i < 16; ++i) acc[a][c][i] = 0.0f;

  // v: f16-packed, matches fragment k-layout; 16 B broadcast per half-group.
  const char* vg = (const char*)(vh + (size_t)n * D_DIM + kq) + hg * 16;
  // u fragments: R5-validated subtile addressing, now f16.
  const char* up = (const char*)uh +
                   ((size_t)(b * 128 + w * 32 + hg)) * 1024 + (size_t)lm * 16;

  FragH c0, c1, d0, d1;
  c0.q = *(const uint4*)(up);        c1.q = *(const uint4*)(up + 512);
  d0.q = *(const uint4*)(up + 2048); d1.q = *(const uint4*)(up + 2560);
  up += 4096;

#pragma unroll 2
  for (int s = 0; s < NSTEP; ++s) {
    FragH n0, n1;                    // depth-2 prefetch; tail over-reads into vh region (allocated)
    n0.q = *(const uint4*)(up);
    n1.q = *(const uint4*)(up + 512);
    up += 2048;
    FragH vv;
    vv.q = *(const uint4*)(vg + s * 32);
    FragH sa0, sa1;
    sa0.v = c0.v * vv.v;             // 4x v_pk_mul_f16
    sa1.v = c1.v * vv.v;
    acc[0][0] = MFMA32H(sa0.v, c0.v, acc[0][0]);
    acc[0][1] = MFMA32H(sa0.v, c1.v, acc[0][1]);
    acc[1][0] = MFMA32H(sa1.v, c0.v, acc[1][0]);
    acc[1][1] = MFMA32H(sa1.v, c1.v, acc[1][1]);
    c0 = d0; c1 = d1; d0 = n0; d1 = n1;
  }

  // ---- R5-validated cross-wave reduce; plain stores to the partial slab ---
  float* slab = part + (size_t)(b * 256 + n) * 4096;
#pragma unroll
  for (int t = 0; t < 4; ++t) {
    __syncthreads();
    {
      const f32x16_t A = acc[t >> 1][t & 1];
      float* rp = &Red[w][l][0];
#pragma unroll
      for (int qq = 0; qq < 4; ++qq)
        *(float4*)(rp + qq * 4) =
            make_float4(A[qq * 4 + 0], A[qq * 4 + 1], A[qq * 4 + 2], A[qq * 4 + 3]);
    }
    __syncthreads();
    {
      const float4 r0 = *(const float4*)(&Red[0][l][w * 4]);
      const float4 r1 = *(const float4*)(&Red[1][l][w * 4]);
      const float4 r2 = *(const float4*)(&Red[2][l][w * 4]);
      const float4 r3 = *(const float4*)(&Red[3][l][w * 4]);
      const int tr = t >> 1, tc = t & 1;
      const int rbase = tr * 32 + w * 8 + ((l >> 5) << 2);
      const int col   = tc * 32 + (l & 31);
      float* op = slab + (size_t)rbase * 64 + col;
      op[0]   = r0.x + r1.x + r2.x + r3.x;
      op[64]  = r0.y + r1.y + r2.y + r3.y;
      op[128] = r0.z + r1.z + r2.z + r3.z;
      op[192] = r0.w + r1.w + r2.w + r3.w;
    }
  }
}

// ---- reduce: out[i] = sum over 4 partial slabs (deterministic, coalesced) --
__global__ __launch_bounds__(256)
void reduce_kernel(const float* __restrict__ part, float* __restrict__ out) {
  const size_t i = ((size_t)blockIdx.x * 256 + threadIdx.x) * 4;
  const float4 a = *(const float4*)(part + i);
  const float4 b = *(const float4*)(part + SLAB + i);
  const float4 c = *(const float4*)(part + 2 * (size_t)SLAB + i);
  const float4 d = *(const float4*)(part + 3 * (size_t)SLAB + i);
  *(float4*)(out + i) = make_float4(a.x + b.x + c.x + d.x,
                                    a.y + b.y + c.y + d.y,
                                    a.z + b.z + c.z + d.z,
                                    a.w + b.w + c.w + d.w);
}

// ---- fallback (tiny ws): R5-validated single-kernel bf16 path -------------
__global__ __launch_bounds__(256)
void gram_fallback_kernel(const float* __restrict__ vin,
                          const float* __restrict__ uf32,
                          float* __restrict__ out)
{
  __shared__ float Red[4][C_DIM][20];

  const int tid = threadIdx.x;
  const int w   = tid >> 6;
  const int l   = tid & 63;
  const int n   = blockIdx.x;
  const int hg  = l >> 5;
  const int lm  = l & 31;
  const int kq  = w * 1024;

  f32x16_t acc[2][2];
#pragma unroll
  for (int a = 0; a < 2; ++a)
#pragma unroll
    for (int c = 0; c < 2; ++c)
#pragma unroll
      for (int i = 0; i < 16; ++i) acc[a][c][i] = 0.0f;

  const char* vg  = (const char*)(vin + (size_t)n * D_DIM + kq) + hg * 32;
  const char* ua  = (const char*)(uf32 + (size_t)lm * D_DIM + kq) + hg * 32;
  const char* ubx = ua + (size_t)32 * D_DIM * 4;
  for (int s = 0; s < 64; ++s) {
    const float4 a0 = *(const float4*)(ua  + (size_t)s * 64);
    const float4 a1 = *(const float4*)(ua  + (size_t)s * 64 + 16);
    const float4 b0 = *(const float4*)(ubx + (size_t)s * 64);
    const float4 b1 = *(const float4*)(ubx + (size_t)s * 64 + 16);
    const float4 va = *(const float4*)(vg + s * 64);
    const float4 vb = *(const float4*)(vg + s * 64 + 16);
    Frag f0, f1, sa0, sa1;
    f0.u[0] = pk_bf16(a0.x, a0.y);  f0.u[1] = pk_bf16(a0.z, a0.w);
    f0.u[2] = pk_bf16(a1.x, a1.y);  f0.u[3] = pk_bf16(a1.z, a1.w);
    f1.u[0] = pk_bf16(b0.x, b0.y);  f1.u[1] = pk_bf16(b0.z, b0.w);
    f1.u[2] = pk_bf16(b1.x, b1.y);  f1.u[3] = pk_bf16(b1.z, b1.w);
    sa0.u[0] = pk_bf16(a0.x * va.x, a0.y * va.y);
    sa0.u[1] = pk_bf16(a0.z * va.z, a0.w * va.w);
    sa0.u[2] = pk_bf16(a1.x * vb.x, a1.y * vb.y);
    sa0.u[3] = pk_bf16(a1.z * vb.z, a1.w * vb.w);
    sa1.u[0] = pk_bf16(b0.x * va.x, b0.y * va.y);
    sa1.u[1] = pk_bf16(b0.z * va.z, b0.w * va.w);
    sa1.u[2] = pk_bf16(b1.x * vb.x, b1.y * vb.y);
    sa1.u[3] = pk_bf16(b1.z * vb.z, b1.w * vb.w);
    acc[0][0] = MFMA32B(sa0.b, f0.b, acc[0][0]);
    acc[0][1] = MFMA32B(sa0.b, f1.b, acc[0][1]);
    acc[1][0] = MFMA32B(sa1.b, f0.b, acc[1][0]);
    acc[1][1] = MFMA32B(sa1.b, f1.b, acc[1][1]);
  }

#pragma unroll
  for (int t = 0; t < 4; ++t) {
    __syncthreads();
    {
      const f32x16_t A = acc[t >> 1][t & 1];
      float* rp = &Red[w][l][0];
#pragma unroll
      for (int qq = 0; qq < 4; ++qq)
        *(float4*)(rp + qq * 4) =
            make_float4(A[qq * 4 + 0], A[qq * 4 + 1], A[qq * 4 + 2], A[qq * 4 + 3]);
    }
    __syncthreads();
    {
      const float4 r0 = *(const float4*)(&Red[0][l][w * 4]);
      const float4 r1 = *(const float4*)(&Red[1][l][w * 4]);
      const float4 r2 = *(const float4*)(&Red[2][l][w * 4]);
      const float4 r3 = *(const float4*)(&Red[3][l][w * 4]);
      const int tr = t >> 1, tc = t & 1;
      const int rbase = tr * 32 + w * 8 + ((l >> 5) << 2);
      const int col   = tc * 32 + (l & 31);
      float* op = out + (size_t)n * 4096 + (size_t)rbase * 64 + col;
      op[0]   = r0.x + r1.x + r2.x + r3.x;
      op[64]  = r0.y + r1.y + r2.y + r3.y;
      op[128] = r0.z + r1.z + r2.z + r3.z;
      op[192] = r0.w + r1.w + r2.w + r3.w;
    }
  }
}

extern "C" void kernel_launch(void* const* d_in, const int* in_sizes, int n_in,
                              void* d_out, int out_size, void* d_ws, size_t ws_size,
                              hipStream_t stream) {
  const float* v   = (const float*)d_in[0];
  const float* u   = (const float*)d_in[1];
  float*       out = (float*)d_out;
  if (ws_size >= ((size_t)20 << 20)) {
    _Float16* uh   = (_Float16*)d_ws;
    _Float16* vh   = (_Float16*)((char*)d_ws + VH_OFF);
    float*    part = (float*)((char*)d_ws + PART_OFF);
    prep_kernel<<<dim3(640), dim3(256), 0, stream>>>(u, v, uh, vh);
    gram_part_kernel<<<dim3(N_DIM * NQ), dim3(256), 0, stream>>>(vh, uh, part);
    reduce_kernel<<<dim3(SLAB / 4 / 256), dim3(256), 0, stream>>>(part, out);
  } else {
    gram_fallback_kernel<<<dim3(N_DIM), dim3(256), 0, stream>>>(v, u, out);
  }
}